// Round 1
// baseline (352.656 us; speedup 1.0000x reference)
//
#include <hip/hip_runtime.h>
#include <hip/hip_bf16.h>

// Problem constants (B=8192, IN=H=1024)
#define BATCH 8192
#define HDIM  1024
#define KDIM  2048   // IN + H concatenated
#define NDIM  4096   // 4*H

__device__ inline unsigned short f2bf(float x) {
    unsigned int u = __float_as_uint(x);
    unsigned int r = (u + 0x7fffu + ((u >> 16) & 1u)) >> 16;
    return (unsigned short)r;
}
__device__ inline float bf2f(unsigned short u) {
    return __uint_as_float((unsigned int)u << 16);
}

// Merged converter:
//  Wb [4096,2048] bf16: row n = [w_i[n] | w_h[n]], w_i half zeroed for rows
//  2048..3071 (chunk i_gc of gi is unused by the reference).
//  Xb [8192,2048] bf16: row r = [input[r] | h_prev[r]]
__global__ __launch_bounds__(256) void convert_kernel(
    const float* __restrict__ wi, const float* __restrict__ wh,
    const float* __restrict__ input, const float* __restrict__ h_prev,
    unsigned short* __restrict__ Wb, unsigned short* __restrict__ Xb)
{
    int idx = blockIdx.x * 256 + threadIdx.x;
    const int NW = NDIM * 512;              // weight-element groups
    float4 v;
    unsigned short* dst;
    if (idx < NW) {
        int n = idx >> 9;
        int k = (idx & 511) << 2;
        if (k < 1024) {
            if (n >= 2048 && n < 3072) v = make_float4(0.f, 0.f, 0.f, 0.f);
            else                       v = *(const float4*)(wi + (size_t)n * 1024 + k);
        } else {
            v = *(const float4*)(wh + (size_t)n * 1024 + (k - 1024));
        }
        dst = Wb + (size_t)n * KDIM + k;
    } else {
        int j = idx - NW;
        int r = j >> 9;
        int k = (j & 511) << 2;
        if (k < 1024) v = *(const float4*)(input  + (size_t)r * 1024 + k);
        else          v = *(const float4*)(h_prev + (size_t)r * 1024 + (k - 1024));
        dst = Xb + (size_t)r * KDIM + k;
    }
    ushort4 o;
    o.x = f2bf(v.x); o.y = f2bf(v.y); o.z = f2bf(v.z); o.w = f2bf(v.w);
    *(ushort4*)dst = o;
}

// ---------------------------------------------------------------------------
// GEMM R5: G[M,N](bf16) = A[M,K](bf16) * Bw[N,K](bf16)^T
// 256x256 tile, 512 threads (8 waves, 2m x 4n of 128x64 wave-tiles), BK=64.
// Double-buffered LDS (128 KB), counted s_waitcnt vmcnt(8) so prefetch loads
// stay in flight across raw s_barrier (T3+T4); 4 quadrant phases per K-tile
// with s_setprio around MFMA clusters (T5). XOR-swizzled LDS k-chunks
// (proven 0-conflict in R2-R4). Linear n-fastest block order (R3 finding).
// ---------------------------------------------------------------------------
#define BM 256
#define BN 256
#define BK 64    // bf16 elems per row; 128 B

typedef __attribute__((ext_vector_type(8))) short bf16x8;
typedef __attribute__((ext_vector_type(4))) float f32x4;

#define BARRIER() { asm volatile("" ::: "memory"); \
                    __builtin_amdgcn_s_barrier();  \
                    asm volatile("" ::: "memory"); }

// 8 global_load_lds per wave: 4 A-rows-groups + 4 B-rows-groups of 8 rows.
// LDS dest is linear (wave-uniform base + lane*16B); swizzle achieved by
// pre-swizzling the GLOBAL source chunk (c_sw), so LDS slot (l&7) of row
// (rbase+srow) holds global chunk (l&7)^srow  ==  logical ^ (row&7).
#define STAGE_TILE(buf, kbase)                                                 \
  {                                                                            \
    _Pragma("unroll") for (int p = 0; p < 4; ++p) {                            \
      const int rbase = wave * 32 + p * 8;                                     \
      __builtin_amdgcn_global_load_lds(                                        \
          (const __attribute__((address_space(1))) void*)(                     \
              A + (size_t)(bm + rbase + srow) * KDIM + (kbase) + c_sw * 8),    \
          (__attribute__((address_space(3))) void*)&As[buf][rbase * BK],       \
          16, 0, 0);                                                           \
      __builtin_amdgcn_global_load_lds(                                        \
          (const __attribute__((address_space(1))) void*)(                     \
              Bw + (size_t)(bn + rbase + srow) * KDIM + (kbase) + c_sw * 8),   \
          (__attribute__((address_space(3))) void*)&Bs[buf][rbase * BK],       \
          16, 0, 0);                                                           \
    }                                                                          \
  }

// 4 quadrant phases; a0 (A m-frags 0-3) dies after phase 1 so its registers
// can be reused for a1 -> peak frag regs 64+32 on top of 128 acc.
#define COMPUTE_TILE(buf)                                                      \
  {                                                                            \
    const unsigned short* __restrict__ Ab = As[buf];                           \
    const unsigned short* __restrict__ Bb = Bs[buf];                           \
    bf16x8 a0[4][2], a1[4][2], b0[2][2], b1[2][2];                             \
    _Pragma("unroll") for (int i = 0; i < 4; ++i)                              \
      _Pragma("unroll") for (int kk = 0; kk < 2; ++kk)                         \
        a0[i][kk] = *(const bf16x8*)&Ab[(wm + i * 16 + ln15) * BK +            \
                                        (((kk * 4 + l16) ^ r7) * 8)];          \
    _Pragma("unroll") for (int j = 0; j < 2; ++j)                              \
      _Pragma("unroll") for (int kk = 0; kk < 2; ++kk)                         \
        b0[j][kk] = *(const bf16x8*)&Bb[(wn + j * 16 + ln15) * BK +            \
                                        (((kk * 4 + l16) ^ r7) * 8)];          \
    __builtin_amdgcn_s_setprio(1);                                             \
    _Pragma("unroll") for (int i = 0; i < 4; ++i)                              \
      _Pragma("unroll") for (int j = 0; j < 2; ++j)                            \
        _Pragma("unroll") for (int kk = 0; kk < 2; ++kk)                       \
          acc[i][j] = __builtin_amdgcn_mfma_f32_16x16x32_bf16(                 \
              a0[i][kk], b0[j][kk], acc[i][j], 0, 0, 0);                       \
    __builtin_amdgcn_s_setprio(0);                                             \
    _Pragma("unroll") for (int j = 0; j < 2; ++j)                              \
      _Pragma("unroll") for (int kk = 0; kk < 2; ++kk)                         \
        b1[j][kk] = *(const bf16x8*)&Bb[(wn + (j + 2) * 16 + ln15) * BK +      \
                                        (((kk * 4 + l16) ^ r7) * 8)];          \
    __builtin_amdgcn_s_setprio(1);                                             \
    _Pragma("unroll") for (int i = 0; i < 4; ++i)                              \
      _Pragma("unroll") for (int j = 0; j < 2; ++j)                            \
        _Pragma("unroll") for (int kk = 0; kk < 2; ++kk)                       \
          acc[i][j + 2] = __builtin_amdgcn_mfma_f32_16x16x32_bf16(             \
              a0[i][kk], b1[j][kk], acc[i][j + 2], 0, 0, 0);                   \
    __builtin_amdgcn_s_setprio(0);                                             \
    _Pragma("unroll") for (int i = 0; i < 4; ++i)                              \
      _Pragma("unroll") for (int kk = 0; kk < 2; ++kk)                         \
        a1[i][kk] = *(const bf16x8*)&Ab[(wm + (i + 4) * 16 + ln15) * BK +      \
                                        (((kk * 4 + l16) ^ r7) * 8)];          \
    __builtin_amdgcn_s_setprio(1);                                             \
    _Pragma("unroll") for (int i = 0; i < 4; ++i)                              \
      _Pragma("unroll") for (int j = 0; j < 2; ++j)                            \
        _Pragma("unroll") for (int kk = 0; kk < 2; ++kk)                       \
          acc[i + 4][j + 2] = __builtin_amdgcn_mfma_f32_16x16x32_bf16(         \
              a1[i][kk], b1[j][kk], acc[i + 4][j + 2], 0, 0, 0);               \
    __builtin_amdgcn_s_setprio(0);                                             \
    __builtin_amdgcn_s_setprio(1);                                             \
    _Pragma("unroll") for (int i = 0; i < 4; ++i)                              \
      _Pragma("unroll") for (int j = 0; j < 2; ++j)                            \
        _Pragma("unroll") for (int kk = 0; kk < 2; ++kk)                       \
          acc[i + 4][j] = __builtin_amdgcn_mfma_f32_16x16x32_bf16(             \
              a1[i][kk], b0[j][kk], acc[i + 4][j], 0, 0, 0);                   \
    __builtin_amdgcn_s_setprio(0);                                             \
  }

__global__ __launch_bounds__(512) void gemm_bt_kernel(
    const unsigned short* __restrict__ A,
    const unsigned short* __restrict__ Bw,
    unsigned short* __restrict__ G,
    int M)
{
    __shared__ unsigned short As[2][BM * BK];   // 2 x 32 KB
    __shared__ unsigned short Bs[2][BN * BK];   // 2 x 32 KB

    const int tid  = threadIdx.x;
    const int lane = tid & 63;
    const int wave = tid >> 6;               // 0..7

    const int bid = blockIdx.x;              // n-fastest linear
    const int bm  = (bid >> 4) * BM;
    const int bn  = (bid & 15) * BN;

    const int wm = (wave >> 2) * 128;        // 0,128
    const int wn = (wave & 3) * 64;          // 0,64,128,192

    // staging: lane l covers row (l>>3) of its 8-row group, LDS chunk (l&7).
    const int srow = lane >> 3;              // 0..7
    const int c_sw = (lane & 7) ^ srow;      // global 16B-chunk to fetch

    const int ln15 = lane & 15;
    const int l16  = lane >> 4;
    const int r7   = lane & 7;

    f32x4 acc[8][4] = {};

    int k0 = 0;
    if (bn >= 2048 && bn < 3072) k0 = 1024;  // w_i half of these rows is zero
    const int nt = (KDIM - k0) / BK;

    STAGE_TILE(0, k0);
    int cur = 0;
    for (int t = 0; t < nt - 1; ++t) {
        STAGE_TILE(cur ^ 1, k0 + (t + 1) * BK);
        // counted wait: the 8 loads just issued stay in flight; the 8 from
        // the previous iteration (this buffer's data) must be done.
        asm volatile("s_waitcnt vmcnt(8)" ::: "memory");
        BARRIER();                           // all waves' tile-t loads landed
        COMPUTE_TILE(cur);
        BARRIER();                           // all waves done reading buf cur
        cur ^= 1;
    }
    asm volatile("s_waitcnt vmcnt(0)" ::: "memory");
    BARRIER();
    COMPUTE_TILE(cur);

    // Epilogue: C/D mapping col=lane&15, row=(lane>>4)*4+reg (m89-verified).
#pragma unroll
    for (int i = 0; i < 8; ++i) {
#pragma unroll
        for (int j = 0; j < 4; ++j) {
#pragma unroll
            for (int r = 0; r < 4; ++r) {
                int row = bm + wm + i * 16 + l16 * 4 + r;
                int col = bn + wn + j * 16 + ln15;
                G[(size_t)row * NDIM + col] = f2bf(acc[i][j][r]);
            }
        }
    }
}

// ---------------------------------------------------------------------------
// Elementwise: wave-per-row, pure shuffle reductions, no barriers / LDS.
// G (bf16) row layout: [s0=i_i+h_i | s1=i_f+h_f | s2=h_g | s3=i_o+h_o]
// Lane l covers cols {j*512 + l*8 + e : j in 0..1, e in 0..7}.
// ---------------------------------------------------------------------------
__device__ inline float sigmoid_f(float x) { return 1.f / (1.f + __expf(-x)); }
// safe fast tanh: exact +/-1 saturation at both ends
__device__ inline float tanh_f(float x) { return 1.f - 2.f / (__expf(2.f * x) + 1.f); }

typedef __attribute__((ext_vector_type(8))) unsigned short us8;

__device__ inline void wstats(const float* x, float& mu, float& rs)
{
    float s = 0.f, q = 0.f;
#pragma unroll
    for (int e = 0; e < 16; ++e) { s += x[e]; q += x[e] * x[e]; }
#pragma unroll
    for (int o = 1; o < 64; o <<= 1) {
        s += __shfl_xor(s, o);
        q += __shfl_xor(q, o);
    }
    mu = s * (1.f / 1024.f);
    float var = q * (1.f / 1024.f) - mu * mu;
    rs = rsqrtf(var + 1e-5f);
}

// 16 bf16 -> fp32 per thread: two 16B ushort8 loads
#define LOADG16(dst, basep)                                            \
    _Pragma("unroll")                                                  \
    for (int j = 0; j < 2; ++j) {                                      \
        us8 t = *(const us8*)((basep) + j * 512 + cbase);              \
        _Pragma("unroll")                                              \
        for (int e = 0; e < 8; ++e) dst[j * 8 + e] = bf2f(t[e]);       \
    }

// 16 fp32 per thread (params / c_prev): four float4 loads
#define LOADF16(dst, basep)                                            \
    _Pragma("unroll")                                                  \
    for (int j = 0; j < 2; ++j) {                                      \
        float4 a = *(const float4*)((basep) + j * 512 + cbase);        \
        float4 b = *(const float4*)((basep) + j * 512 + cbase + 4);    \
        dst[j * 8 + 0] = a.x; dst[j * 8 + 1] = a.y;                    \
        dst[j * 8 + 2] = a.z; dst[j * 8 + 3] = a.w;                    \
        dst[j * 8 + 4] = b.x; dst[j * 8 + 5] = b.y;                    \
        dst[j * 8 + 6] = b.z; dst[j * 8 + 7] = b.w;                    \
    }

__global__ __launch_bounds__(256) void lstm_ew_kernel(
    const unsigned short* __restrict__ G,
    const float* __restrict__ c_prev,
    const float* __restrict__ p0g, const float* __restrict__ p0b,
    const float* __restrict__ p1g, const float* __restrict__ p1b,
    const float* __restrict__ p2g, const float* __restrict__ p2b,
    const float* __restrict__ p3g, const float* __restrict__ p3b,
    const float* __restrict__ p4g, const float* __restrict__ p4b,
    float* __restrict__ out_h, float* __restrict__ out_c,
    int row_base)
{
    const int lane  = threadIdx.x & 63;
    const int wave  = threadIdx.x >> 6;
    const int r     = blockIdx.x * 4 + wave;
    const int grow  = row_base + r;
    const int cbase = lane * 8;

    const unsigned short* Grow = G + (size_t)r * NDIM;

    float tmp[16], pg[16], pb[16];
    float ig[16], cm[16], og[16];
    float mu, rs;

    // i gate: sigmoid(LN(i_i+h_i; ln_i))
    LOADG16(tmp, Grow);
    wstats(tmp, mu, rs);
    LOADF16(pg, p0g); LOADF16(pb, p0b);
#pragma unroll
    for (int e = 0; e < 16; ++e)
        ig[e] = sigmoid_f((tmp[e] - mu) * rs * pg[e] + pb[e]);

    // f gate: sigmoid(LN(i_f+h_f; ln_h)); cm = f * c_prev
    LOADG16(tmp, Grow + 1024);
    wstats(tmp, mu, rs);
    LOADF16(pg, p1g); LOADF16(pb, p1b);
    LOADF16(cm, c_prev + (size_t)grow * HDIM);
#pragma unroll
    for (int e = 0; e < 16; ++e)
        cm[e] *= sigmoid_f((tmp[e] - mu) * rs * pg[e] + pb[e]);

    // g gate: tanh(LN(i_g + h_g; ln_g))  <- faithful bug: i_g is sigmoided gate
    LOADG16(tmp, Grow + 2048);
#pragma unroll
    for (int e = 0; e < 16; ++e) tmp[e] += ig[e];
    wstats(tmp, mu, rs);
    LOADF16(pg, p2g); LOADF16(pb, p2b);
#pragma unroll
    for (int e = 0; e < 16; ++e)
        cm[e] += ig[e] * tanh_f((tmp[e] - mu) * rs * pg[e] + pb[e]);

    // o gate: sigmoid(LN(i_o+h_o; ln_o))
    LOADG16(tmp, Grow + 3072);
    wstats(tmp, mu, rs);
    LOADF16(pg, p3g); LOADF16(pb, p3b);
#pragma unroll
    for (int e = 0; e < 16; ++e)
        og[e] = sigmoid_f((tmp[e] - mu) * rs * pg[e] + pb[e]);

    // c_new = LN(cm; ln_c); h_new = o * tanh(c_new)
    wstats(cm, mu, rs);
    LOADF16(pg, p4g); LOADF16(pb, p4b);
    float cn[16], hn[16];
#pragma unroll
    for (int e = 0; e < 16; ++e) {
        cn[e] = (cm[e] - mu) * rs * pg[e] + pb[e];
        hn[e] = og[e] * tanh_f(cn[e]);
    }

    float* oh = out_h + (size_t)grow * HDIM;
    float* oc = out_c + (size_t)grow * HDIM;
#pragma unroll
    for (int j = 0; j < 2; ++j) {
        *(float4*)(oh + j * 512 + cbase) =
            make_float4(hn[j*8+0], hn[j*8+1], hn[j*8+2], hn[j*8+3]);
        *(float4*)(oh + j * 512 + cbase + 4) =
            make_float4(hn[j*8+4], hn[j*8+5], hn[j*8+6], hn[j*8+7]);
        *(float4*)(oc + j * 512 + cbase) =
            make_float4(cn[j*8+0], cn[j*8+1], cn[j*8+2], cn[j*8+3]);
        *(float4*)(oc + j * 512 + cbase + 4) =
            make_float4(cn[j*8+4], cn[j*8+5], cn[j*8+6], cn[j*8+7]);
    }
}

extern "C" void kernel_launch(void* const* d_in, const int* in_sizes, int n_in,
                              void* d_out, int out_size, void* d_ws, size_t ws_size,
                              hipStream_t stream)
{
    const float* input  = (const float*)d_in[0];
    const float* h_prev = (const float*)d_in[1];
    const float* c_prev = (const float*)d_in[2];
    const float* w_i    = (const float*)d_in[3];
    const float* w_h    = (const float*)d_in[4];
    const float* lng[10];
    for (int i = 0; i < 10; ++i) lng[i] = (const float*)d_in[5 + i];

    // Workspace: Xb bf16 [8192,2048] | Wb bf16 [4096,2048] | G bf16 [chunk,4096]
    unsigned short* Xb = (unsigned short*)d_ws;
    size_t xb_bytes = (size_t)BATCH * KDIM * 2;
    unsigned short* Wb = (unsigned short*)((char*)d_ws + xb_bytes);
    size_t wb_bytes = (size_t)NDIM * KDIM * 2;
    unsigned short* G = (unsigned short*)((char*)d_ws + xb_bytes + wb_bytes);

    size_t g_avail = (ws_size > xb_bytes + wb_bytes) ? (ws_size - xb_bytes - wb_bytes) : 0;
    long max_rows = (long)(g_avail / ((size_t)NDIM * sizeof(unsigned short)));
    int chunk = (max_rows >= BATCH) ? BATCH : (int)((max_rows / BM) * BM);
    if (chunk <= 0) chunk = BM;   // last-resort assumption

    convert_kernel<<<(NDIM * 512 + BATCH * 512) / 256, 256, 0, stream>>>(
        w_i, w_h, input, h_prev, Wb, Xb);

    float* out_h = (float*)d_out;
    float* out_c = out_h + (size_t)BATCH * HDIM;

    for (int rb = 0; rb < BATCH; rb += chunk) {
        int rows = (BATCH - rb < chunk) ? (BATCH - rb) : chunk;
        gemm_bt_kernel<<<(rows / BM) * (NDIM / BN), 512, 0, stream>>>(
            Xb + (size_t)rb * KDIM, Wb, G, rows);
        lstm_ew_kernel<<<rows / 4, 256, 0, stream>>>(
            G, c_prev, lng[0], lng[1], lng[2], lng[3], lng[4],
            lng[5], lng[6], lng[7], lng[8], lng[9], out_h, out_c, rb);
    }
}